// Round 1
// baseline (93.769 us; speedup 1.0000x reference)
//
#include <hip/hip_runtime.h>

#define WAVES_PER_BLOCK 4
#define NBATCH 2048
#define NROWS 8
#define NDIM 64
#define ROW_PITCH 65   // +1 pad: unpadded stride-64 rows alias to one bank (8-way conflict)

__global__ __launch_bounds__(WAVES_PER_BLOCK * 64)
void assignment_kernel(const float* __restrict__ y_true,
                       const float* __restrict__ y_pred,
                       float* __restrict__ out) {
    __shared__ float s_yt[WAVES_PER_BLOCK][NROWS * ROW_PITCH];
    __shared__ float s_yp[WAVES_PER_BLOCK][NROWS * ROW_PITCH];
    __shared__ float s_C [WAVES_PER_BLOCK][64];
    __shared__ float s_dp[WAVES_PER_BLOCK][256];

    const int lane = threadIdx.x & 63;
    const int wv   = threadIdx.x >> 6;
    const int b    = blockIdx.x * WAVES_PER_BLOCK + wv;

    const float* tb = y_true + (size_t)b * (NROWS * NDIM);
    const float* pb = y_pred + (size_t)b * (NROWS * NDIM);

    // ---- Stage batch into LDS: 512 floats each, float4 coalesced ----
    // iteration k: lane loads float4 at linear index 4*lane + 256*k
    #pragma unroll
    for (int k = 0; k < 2; ++k) {
        int l = 4 * lane + 256 * k;          // 0..508, 4-aligned, same row per float4
        int row = l >> 6;                    // NDIM=64 divides cleanly
        int d   = l & 63;
        float4 vt = *(const float4*)(tb + l);
        float4 vp = *(const float4*)(pb + l);
        float* dt = &s_yt[wv][row * ROW_PITCH + d];
        float* dpp = &s_yp[wv][row * ROW_PITCH + d];
        dt[0] = vt.x; dt[1] = vt.y; dt[2] = vt.z; dt[3] = vt.w;
        dpp[0] = vp.x; dpp[1] = vp.y; dpp[2] = vp.z; dpp[3] = vp.w;
    }
    __syncthreads();

    // ---- Cost matrix: lane t -> (i,j) = (t>>3, t&7) ----
    {
        const int i = lane >> 3;
        const int j = lane & 7;
        const float* ai = &s_yt[wv][i * ROW_PITCH];
        const float* pj = &s_yp[wv][j * ROW_PITCH];
        float acc = 0.0f;
        #pragma unroll
        for (int d = 0; d < NDIM; ++d) {
            float df = ai[d] - pj[d];
            acc = fmaf(df, df, acc);
        }
        s_C[wv][lane] = acc;                 // unnormalized: fold /64 into final scale
    }
    if (lane == 0) s_dp[wv][0] = 0.0f;
    __syncthreads();

    // ---- Held-Karp DP: dp[mask] = min cost assigning rows 0..k-1 to cols in mask ----
    #pragma unroll
    for (int lv = 1; lv <= 8; ++lv) {
        const int r8 = (lv - 1) * 8;
        #pragma unroll
        for (int q = 0; q < 4; ++q) {
            int m = q * 64 + lane;
            if (__popc(m) == lv) {
                float best = 1e30f;
                #pragma unroll
                for (int j = 0; j < 8; ++j) {
                    if (m & (1 << j)) {
                        float v = s_dp[wv][m ^ (1 << j)] + s_C[wv][r8 + j];
                        best = fminf(best, v);
                    }
                }
                s_dp[wv][m] = best;
            }
        }
        __syncthreads();
    }

    // ---- Accumulate: mean over D (/64), /N (/8), mean over B (/2048) ----
    if (lane == 0) {
        const float scale = 1.0f / (64.0f * 8.0f * 2048.0f);
        atomicAdd(out, s_dp[wv][255] * scale);
    }
}

extern "C" void kernel_launch(void* const* d_in, const int* in_sizes, int n_in,
                              void* d_out, int out_size, void* d_ws, size_t ws_size,
                              hipStream_t stream) {
    const float* y_true = (const float*)d_in[0];
    const float* y_pred = (const float*)d_in[1];
    float* out = (float*)d_out;

    hipMemsetAsync(out, 0, sizeof(float), stream);

    const int blocks = NBATCH / WAVES_PER_BLOCK;   // 512
    assignment_kernel<<<blocks, WAVES_PER_BLOCK * 64, 0, stream>>>(y_true, y_pred, out);
}

// Round 2
// 69.642 us; speedup vs baseline: 1.3464x; 1.3464x over previous
//
#include <hip/hip_runtime.h>

#define WAVES_PER_BLOCK 4
#define NBATCH 2048
#define NROWS 8
#define NDIM 64
#define ROW_PITCH 68   // 16B-aligned rows (68*4=272B) -> float4 LDS reads; rows spread banks
#define NBLOCKS (NBATCH / WAVES_PER_BLOCK)   // 512

// Stage 1: one wave per batch. Build 8x8 cost matrix, Held-Karp DP over 256
// subsets, one partial per block written to d_ws (no atomics -> no same-address
// serialization, which cost ~50us in round 1).
__global__ __launch_bounds__(WAVES_PER_BLOCK * 64)
void assignment_stage1(const float* __restrict__ y_true,
                       const float* __restrict__ y_pred,
                       float* __restrict__ partials) {
    __shared__ float s_yt[WAVES_PER_BLOCK][NROWS * ROW_PITCH];
    __shared__ float s_yp[WAVES_PER_BLOCK][NROWS * ROW_PITCH];
    __shared__ float s_C [WAVES_PER_BLOCK][64];
    __shared__ float s_dp[WAVES_PER_BLOCK][256];
    __shared__ float s_wsum[WAVES_PER_BLOCK];

    const int lane = threadIdx.x & 63;
    const int wv   = threadIdx.x >> 6;
    const int b    = blockIdx.x * WAVES_PER_BLOCK + wv;

    const float* tb = y_true + (size_t)b * (NROWS * NDIM);
    const float* pb = y_pred + (size_t)b * (NROWS * NDIM);

    // ---- Stage batch into LDS: 512 floats each, float4 coalesced ----
    #pragma unroll
    for (int k = 0; k < 2; ++k) {
        int l   = 4 * lane + 256 * k;        // 0..508, float4-aligned, within one row
        int row = l >> 6;
        int d   = l & 63;
        float4 vt = *(const float4*)(tb + l);
        float4 vp = *(const float4*)(pb + l);
        *(float4*)&s_yt[wv][row * ROW_PITCH + d] = vt;
        *(float4*)&s_yp[wv][row * ROW_PITCH + d] = vp;
    }
    __syncthreads();

    // ---- Cost matrix: lane t -> (i,j) = (t>>3, t&7), ds_read_b128 x2 per 4 dims ----
    {
        const int i = lane >> 3;
        const int j = lane & 7;
        const float* ai = &s_yt[wv][i * ROW_PITCH];
        const float* pj = &s_yp[wv][j * ROW_PITCH];
        float a0 = 0.f, a1 = 0.f, a2 = 0.f, a3 = 0.f;
        #pragma unroll
        for (int d = 0; d < NDIM; d += 4) {
            float4 va = *(const float4*)(ai + d);
            float4 vp = *(const float4*)(pj + d);
            float d0 = va.x - vp.x, d1 = va.y - vp.y;
            float d2 = va.z - vp.z, d3 = va.w - vp.w;
            a0 = fmaf(d0, d0, a0); a1 = fmaf(d1, d1, a1);
            a2 = fmaf(d2, d2, a2); a3 = fmaf(d3, d3, a3);
        }
        s_C[wv][lane] = (a0 + a1) + (a2 + a3);   // /64 folded into final scale
    }
    if (lane == 0) s_dp[wv][0] = 0.0f;
    __syncthreads();

    // ---- Held-Karp DP: dp[mask] = min cost assigning rows 0..lv-1 to cols in mask ----
    #pragma unroll
    for (int lv = 1; lv <= 8; ++lv) {
        const int r8 = (lv - 1) * 8;
        #pragma unroll
        for (int q = 0; q < 4; ++q) {
            int m = q * 64 + lane;
            if (__popc(m) == lv) {
                float best = 1e30f;
                #pragma unroll
                for (int j = 0; j < 8; ++j) {
                    if (m & (1 << j)) {
                        float v = s_dp[wv][m ^ (1 << j)] + s_C[wv][r8 + j];
                        best = fminf(best, v);
                    }
                }
                s_dp[wv][m] = best;
            }
        }
        __syncthreads();
    }

    // ---- Block partial: sum 4 wave results, single uncontended store ----
    if (lane == 0) s_wsum[wv] = s_dp[wv][255];
    __syncthreads();
    if (threadIdx.x == 0)
        partials[blockIdx.x] = (s_wsum[0] + s_wsum[1]) + (s_wsum[2] + s_wsum[3]);
}

// Stage 2: one block reduces 512 partials -> scalar. Overwrites poisoned d_out
// directly (no memset node needed).
__global__ __launch_bounds__(256)
void assignment_stage2(const float* __restrict__ partials,
                       float* __restrict__ out) {
    __shared__ float s[WAVES_PER_BLOCK];
    const int t = threadIdx.x;
    float v = partials[t] + partials[t + 256];
    #pragma unroll
    for (int off = 32; off > 0; off >>= 1)
        v += __shfl_down(v, off, 64);
    if ((t & 63) == 0) s[t >> 6] = v;
    __syncthreads();
    if (t == 0)
        out[0] = ((s[0] + s[1]) + (s[2] + s[3])) * (1.0f / (64.0f * 8.0f * 2048.0f));
}

extern "C" void kernel_launch(void* const* d_in, const int* in_sizes, int n_in,
                              void* d_out, int out_size, void* d_ws, size_t ws_size,
                              hipStream_t stream) {
    const float* y_true = (const float*)d_in[0];
    const float* y_pred = (const float*)d_in[1];
    float* partials = (float*)d_ws;
    float* out = (float*)d_out;

    assignment_stage1<<<NBLOCKS, WAVES_PER_BLOCK * 64, 0, stream>>>(y_true, y_pred, partials);
    assignment_stage2<<<1, 256, 0, stream>>>(partials, out);
}

// Round 3
// 65.376 us; speedup vs baseline: 1.4343x; 1.0652x over previous
//
#include <hip/hip_runtime.h>

#define NBATCH 2048
#define NROWS 8
#define NDIM 64
#define ROW_PITCH 68   // 16B-aligned rows (272B) -> float4 LDS reads, rows spread banks

// Stage 1: one wave (64 threads) per batch, 2048 blocks. C-matrix from LDS-staged
// inputs; Held-Karp DP entirely in registers via lane shuffles:
//   dp[mask] lives at register q = mask>>6, lane = mask&63.
//   dp[m ^ (1<<j)]: j<6 -> __shfl_xor(dp_q, 1<<j); j=6,7 -> dp_{q^1}/dp_{q^2} same lane.
// Zero barriers in the DP (R2 had 8 __syncthreads + LDS round-trips per batch).
__global__ __launch_bounds__(64)
void assignment_stage1(const float* __restrict__ y_true,
                       const float* __restrict__ y_pred,
                       float* __restrict__ partials) {
    __shared__ float s_yt[NROWS * ROW_PITCH];
    __shared__ float s_yp[NROWS * ROW_PITCH];

    const int lane = threadIdx.x;
    const int b    = blockIdx.x;
    const float* tb = y_true + (size_t)b * (NROWS * NDIM);
    const float* pb = y_pred + (size_t)b * (NROWS * NDIM);

    // ---- Stage 512 floats per array into LDS, float4 coalesced ----
    #pragma unroll
    for (int k = 0; k < 2; ++k) {
        int l   = 4 * lane + 256 * k;
        int row = l >> 6;
        int d   = l & 63;
        *(float4*)&s_yt[row * ROW_PITCH + d] = *(const float4*)(tb + l);
        *(float4*)&s_yp[row * ROW_PITCH + d] = *(const float4*)(pb + l);
    }
    __syncthreads();   // single-wave block: near-free

    // ---- C[i][j] in lane 8i+j (unnormalized SSD; /64 folded into final scale) ----
    float myC;
    {
        const int i = lane >> 3;
        const int j = lane & 7;
        const float* ai = &s_yt[i * ROW_PITCH];
        const float* pj = &s_yp[j * ROW_PITCH];
        float a0 = 0.f, a1 = 0.f, a2 = 0.f, a3 = 0.f;
        #pragma unroll
        for (int d = 0; d < NDIM; d += 4) {
            float4 va = *(const float4*)(ai + d);
            float4 vp = *(const float4*)(pj + d);
            float d0 = va.x - vp.x, d1 = va.y - vp.y;
            float d2 = va.z - vp.z, d3 = va.w - vp.w;
            a0 = fmaf(d0, d0, a0); a1 = fmaf(d1, d1, a1);
            a2 = fmaf(d2, d2, a2); a3 = fmaf(d3, d3, a3);
        }
        myC = (a0 + a1) + (a2 + a3);
    }

    // ---- Register Held-Karp over 256 masks ----
    const float INF = 1e30f;
    float dp[4];
    dp[0] = (lane == 0) ? 0.f : INF;
    dp[1] = INF; dp[2] = INF; dp[3] = INF;

    #pragma unroll
    for (int lv = 1; lv <= 8; ++lv) {
        const int r8 = (lv - 1) * 8;
        float c[8];
        #pragma unroll
        for (int j = 0; j < 8; ++j)
            c[j] = __shfl(myC, r8 + j, 64);     // compile-time lane -> v_readlane

        float nd[4];
        #pragma unroll
        for (int q = 0; q < 4; ++q) {
            const int m = q * 64 + lane;
            float best = INF;
            #pragma unroll
            for (int j = 0; j < 6; ++j) {
                float v = __shfl_xor(dp[q], 1 << j, 64) + c[j];
                best = ((m >> j) & 1) ? fminf(best, v) : best;   // cndmask, no branch
            }
            if (q & 1) best = fminf(best, dp[q ^ 1] + c[6]);     // bit6 of m == q&1 (compile-time)
            if (q & 2) best = fminf(best, dp[q ^ 2] + c[7]);     // bit7 of m == q>>1
            nd[q] = best;
        }
        #pragma unroll
        for (int q = 0; q < 4; ++q) {
            const int m = q * 64 + lane;
            dp[q] = (__popc(m) == lv) ? nd[q] : dp[q];
        }
    }

    // dp[255] = register 3, lane 63
    float r = __shfl(dp[3], 63, 64);
    if (lane == 0) partials[b] = r;
}

// Stage 2: one block reduces 2048 partials -> scalar; overwrites poisoned d_out.
__global__ __launch_bounds__(256)
void assignment_stage2(const float* __restrict__ partials,
                       float* __restrict__ out) {
    __shared__ float s[4];
    const int t = threadIdx.x;
    float v = 0.f;
    #pragma unroll
    for (int k = 0; k < 8; ++k) v += partials[t + 256 * k];
    #pragma unroll
    for (int off = 32; off > 0; off >>= 1)
        v += __shfl_down(v, off, 64);
    if ((t & 63) == 0) s[t >> 6] = v;
    __syncthreads();
    if (t == 0)
        out[0] = ((s[0] + s[1]) + (s[2] + s[3])) * (1.0f / (64.0f * 8.0f * 2048.0f));
}

extern "C" void kernel_launch(void* const* d_in, const int* in_sizes, int n_in,
                              void* d_out, int out_size, void* d_ws, size_t ws_size,
                              hipStream_t stream) {
    const float* y_true = (const float*)d_in[0];
    const float* y_pred = (const float*)d_in[1];
    float* partials = (float*)d_ws;
    float* out = (float*)d_out;

    assignment_stage1<<<NBATCH, 64, 0, stream>>>(y_true, y_pred, partials);
    assignment_stage2<<<1, 256, 0, stream>>>(partials, out);
}